// Round 12
// baseline (337.919 us; speedup 1.0000x reference)
//
#include <hip/hip_runtime.h>

typedef __attribute__((ext_vector_type(8))) short short8;
typedef __attribute__((ext_vector_type(4))) float f32x4;
typedef __attribute__((ext_vector_type(2))) float f32x2;

#define NODE_D 128
#define ECH 4096           // edges per counting/scatter chunk (small -> fill all CUs)
#define PSH 9              // partition = 512 consecutive dst nodes
// NOTE: pipeline assumes N <= 131072 (src packs into 17 bits; NP <= 256)

__device__ __forceinline__ float bf2f(ushort u) {
    union { uint i; float f; } c; c.i = ((uint)u) << 16; return c.f;
}
__device__ __forceinline__ ushort f2bf(float f) {
    union { float f; uint i; } c; c.f = f;
    return (ushort)((c.i + 0x7FFF + ((c.i >> 16) & 1)) >> 16);
}
__device__ __forceinline__ uchar f2e4m3(float f) {
    uint w = (uint)__builtin_amdgcn_cvt_pk_fp8_f32(f, f, 0, false);
    return (uchar)(w & 0xff);
}

// ---------- fused: per-chunk partition histogram (blocks 0..NC) + weight cvt ----------
__global__ __launch_bounds__(256) void k_count(const int* __restrict__ dst,
                                               int* __restrict__ cm,
                                               int E, int NC,
                                               const float* __restrict__ s0, const float* __restrict__ s1,
                                               const float* __restrict__ s2, const float* __restrict__ s3,
                                               const float* __restrict__ s4, const float* __restrict__ s5,
                                               const float* __restrict__ s6, ushort* __restrict__ wdst) {
    if ((int)blockIdx.x >= NC) {
        int i = ((int)blockIdx.x - NC) * 256 + threadIdx.x;
        if (i >= 98304) return;
        const float* s; int off;
        if (i < 16384)      { s = s0; off = i; }
        else if (i < 32768) { s = s1; off = i - 16384; }
        else if (i < 49152) { s = s2; off = i - 32768; }
        else if (i < 65536) { s = s3; off = i - 49152; }
        else if (i < 81920) { s = s4; off = i - 65536; }
        else if (i < 90112) { s = s5; off = i - 81920; }
        else                { s = s6; off = i - 90112; }
        wdst[i] = f2bf(s[off]);
        return;
    }
    __shared__ int lh[256];
    lh[threadIdx.x] = 0;
    __syncthreads();
    int c = blockIdx.x;
    int lo = c * ECH, hi = min(lo + ECH, E);
    for (int i = lo + (int)threadIdx.x; i < hi; i += 256)
        atomicAdd(&lh[dst[i] >> PSH], 1);
    __syncthreads();
    cm[c * 256 + threadIdx.x] = lh[threadIdx.x];
}

// ---------- single block: partition-major scan of cm -> om, pbase; rowptr[N]=E ----------
__global__ __launch_bounds__(256) void k_pscan(const int* __restrict__ cm,
                                               int* __restrict__ om,
                                               int* __restrict__ pbase,
                                               int* __restrict__ rowptrN,
                                               int NC, int NP, int E) {
    __shared__ int ts[256];
    int p = threadIdx.x;
    int s = 0;
    if (p < NP)
        for (int c = 0; c < NC; ++c) s += cm[c * 256 + p];
    ts[p] = s;
    __syncthreads();
    for (int st = 1; st < 256; st <<= 1) {
        int add = (p >= st) ? ts[p - st] : 0;
        __syncthreads();
        ts[p] += add;
        __syncthreads();
    }
    int base = ts[p] - s;   // exclusive
    if (p < NP) {
        int run = base;
        for (int c = 0; c < NC; ++c) {
            om[c * 256 + p] = run;
            run += cm[c * 256 + p];
        }
        pbase[p] = base;
    }
    if (p == 0) { pbase[NP] = E; rowptrN[0] = E; }
}

// ---------- deterministic scatter: edges -> partition-major packed ebuf ----------
// packed: bits 0-16 = src, bits 17-25 = local node (d & 511)
__global__ __launch_bounds__(256) void k_scatter3(const int* __restrict__ src,
                                                  const int* __restrict__ dst,
                                                  const int* __restrict__ om,
                                                  uint* __restrict__ ebuf, int E) {
    __shared__ int cur[256];
    int c = blockIdx.x;
    cur[threadIdx.x] = om[c * 256 + threadIdx.x];
    __syncthreads();
    int lo = c * ECH, hi = min(lo + ECH, E);
    for (int i = lo + (int)threadIdx.x; i < hi; i += 256) {
        int d = dst[i];
        int pos = atomicAdd(&cur[d >> PSH], 1);
        ebuf[pos] = ((uint)(d & 511) << 17) | (uint)src[i];
    }
}

// ---------- per-partition local CSR: LDS hist -> LDS scan -> rowptr + col ----------
__global__ __launch_bounds__(256) void k_local(const uint* __restrict__ ebuf,
                                               const int* __restrict__ pbase,
                                               int* __restrict__ rowptr,
                                               int* __restrict__ col, int N) {
    __shared__ int hist[512];
    __shared__ int cur[512];
    __shared__ int ts[256];
    int p = blockIdx.x;
    int t = threadIdx.x;
    int lo = pbase[p], hi = pbase[p + 1];
    hist[t] = 0; hist[t + 256] = 0;
    __syncthreads();
    for (int j = lo + t; j < hi; j += 256)
        atomicAdd(&hist[ebuf[j] >> 17], 1);
    __syncthreads();
    int v0 = hist[2 * t], v1 = hist[2 * t + 1];
    int s = v0 + v1;
    ts[t] = s;
    __syncthreads();
    for (int st = 1; st < 256; st <<= 1) {
        int add = (t >= st) ? ts[t - st] : 0;
        __syncthreads();
        ts[t] += add;
        __syncthreads();
    }
    int excl = ts[t] - s + lo;
    int node0 = (p << PSH) + 2 * t;
    if (node0 < N) rowptr[node0] = excl;
    if (node0 + 1 < N) rowptr[node0 + 1] = excl + v0;
    cur[2 * t] = excl;
    cur[2 * t + 1] = excl + v0;
    __syncthreads();
    for (int j = lo + t; j < hi; j += 256) {
        uint e = ebuf[j];
        int pos = atomicAdd(&cur[e >> 17], 1);
        col[pos] = (int)(e & 0x1FFFF);
    }
}

// ---------- mean aggregation over fp8, packed-VALU masked gather ----------
// 16 lanes x uint2 (8 fp8 cols) cover a 128B row; 4 edge-groups per wave,
// window 8 edges; f32x2 accumulators -> v_pk_fma; reduce via shfl_xor 16/32.
__global__ __launch_bounds__(256) void k_aggf(const uchar* __restrict__ hq,
                                              const int* __restrict__ rowptr,
                                              const int* __restrict__ col,
                                              ushort* __restrict__ mean, int N) {
    int node = blockIdx.x * 4 + (threadIdx.x >> 6);
    if (node >= N) return;
    int lane = threadIdx.x & 63;
    int grp  = lane >> 4;          // 4 edge groups
    int l16  = lane & 15;
    int beg = rowptr[node];
    int end = rowptr[node + 1];
    float inv = 1.f / fmaxf((float)(end - beg), 1.f);
    const uchar* base = hq + l16 * 8;
    f32x2 a01 = {0.f, 0.f}, a23 = {0.f, 0.f}, a45 = {0.f, 0.f}, a67 = {0.f, 0.f};
    for (int jb0 = beg; jb0 < end; jb0 += 8) {
        #pragma unroll
        for (int q = 0; q < 2; ++q) {
            int j = jb0 + grp * 2 + q;
            int s = col[j < end ? j : end - 1];
            uint2 v = *(const uint2*)(base + (size_t)s * 128);
            float m = (j < end) ? 1.f : 0.f;
            f32x2 mk = {m, m};
            a01 += mk * __builtin_amdgcn_cvt_pk_f32_fp8(v.x, false);
            a23 += mk * __builtin_amdgcn_cvt_pk_f32_fp8(v.x, true);
            a45 += mk * __builtin_amdgcn_cvt_pk_f32_fp8(v.y, false);
            a67 += mk * __builtin_amdgcn_cvt_pk_f32_fp8(v.y, true);
        }
    }
    float r[8] = {a01[0], a01[1], a23[0], a23[1], a45[0], a45[1], a67[0], a67[1]};
    #pragma unroll
    for (int i = 0; i < 8; ++i) {
        r[i] += __shfl_xor(r[i], 16);
        r[i] += __shfl_xor(r[i], 32);
    }
    if (lane < 16) {
        uint4 o;
        o.x = (uint)f2bf(r[0] * inv) | ((uint)f2bf(r[1] * inv) << 16);
        o.y = (uint)f2bf(r[2] * inv) | ((uint)f2bf(r[3] * inv) << 16);
        o.z = (uint)f2bf(r[4] * inv) | ((uint)f2bf(r[5] * inv) << 16);
        o.w = (uint)f2bf(r[6] * inv) | ((uint)f2bf(r[7] * inv) << 16);
        *(uint4*)(mean + (size_t)node * 128 + l16 * 8) = o;
    }
}

// ---------- MFMA dense: out = A0@W0^T (+ A1@W1^T) [+bias] [+relu] ----------
// OMODE: 0=bf16, 2=bf16+fp8copy, 3=fp8 only.
template<int OD, bool DUAL, bool RELU, int OMODE, bool A0F32>
__global__ __launch_bounds__(256) void k_mm(const void* __restrict__ A0,
                                            const ushort* __restrict__ A1,
                                            const ushort* __restrict__ W0,
                                            const ushort* __restrict__ W1,
                                            const float* __restrict__ bias,
                                            void* __restrict__ outp,
                                            uchar* __restrict__ f8out, int N) {
    constexpr int NK    = DUAL ? 4 : 2;
    constexpr int M_REP = (OD == 128) ? 4 : 2;
    constexpr int N_REP = 4;
    constexpr int WROWS = M_REP * 16;

    __shared__ __align__(16) ushort sA[128 * 64];
    __shared__ __align__(16) ushort sW[OD * 64];

    const int t    = threadIdx.x;
    const int wid  = t >> 6;
    const int lane = t & 63;
    const int l15  = lane & 15;
    const int lhi  = lane >> 4;
    const int r0   = blockIdx.x * 128;

    int wm, wn0;
    if (OD == 128) { wm = wid >> 1; wn0 = (wid & 1) * 64; }
    else           { wm = wid;      wn0 = 0; }

    f32x4 zero = {0.f, 0.f, 0.f, 0.f};
    f32x4 acc[M_REP][N_REP];
    #pragma unroll
    for (int m = 0; m < M_REP; ++m)
        #pragma unroll
        for (int n = 0; n < N_REP; ++n) acc[m][n] = zero;

    const ushort* A0b = (const ushort*)A0;
    const float*  A0f = (const float*)A0;

    for (int kc = 0; kc < NK; ++kc) {
        const ushort* Ws = (DUAL && kc >= 2) ? W1 : W0;
        const ushort* As = (DUAL && kc >= 2) ? A1 : A0b;
        const int kloc = (kc & 1) * 64;

        __syncthreads();
        #pragma unroll
        for (int it = 0; it < 4; ++it) {
            int slot = it * 256 + t;
            int row = slot >> 3, k8 = slot & 7;
            int gr = r0 + row; if (gr >= N) gr = N - 1;
            short8 v;
            if (A0F32 && kc < 2) {
                float4 p = *(const float4*)(A0f + (size_t)gr * 128 + kloc + k8 * 8);
                float4 q = *(const float4*)(A0f + (size_t)gr * 128 + kloc + k8 * 8 + 4);
                v[0] = (short)f2bf(p.x); v[1] = (short)f2bf(p.y);
                v[2] = (short)f2bf(p.z); v[3] = (short)f2bf(p.w);
                v[4] = (short)f2bf(q.x); v[5] = (short)f2bf(q.y);
                v[6] = (short)f2bf(q.z); v[7] = (short)f2bf(q.w);
            } else {
                v = *(const short8*)(As + (size_t)gr * 128 + kloc + k8 * 8);
            }
            *(short8*)((char*)sA + ((row * 128 + k8 * 16) ^ ((row & 7) << 4))) = v;
        }
        #pragma unroll
        for (int it = 0; it < OD / 32; ++it) {
            int slot = it * 256 + t;
            int row = slot >> 3, k8 = slot & 7;
            short8 v = *(const short8*)(Ws + (size_t)row * 128 + kloc + k8 * 8);
            *(short8*)((char*)sW + ((row * 128 + k8 * 16) ^ ((row & 7) << 4))) = v;
        }
        __syncthreads();

        #pragma unroll
        for (int kb = 0; kb < 2; ++kb) {
            short8 af[M_REP], bfr[N_REP];
            #pragma unroll
            for (int m = 0; m < M_REP; ++m) {
                int row = wm * WROWS + m * 16 + l15;
                af[m] = *(const short8*)((const char*)sA +
                        ((row * 128 + kb * 64 + lhi * 16) ^ ((row & 7) << 4)));
            }
            #pragma unroll
            for (int n = 0; n < N_REP; ++n) {
                int colr = wn0 + n * 16 + l15;
                bfr[n] = *(const short8*)((const char*)sW +
                         ((colr * 128 + kb * 64 + lhi * 16) ^ ((colr & 7) << 4)));
            }
            #pragma unroll
            for (int m = 0; m < M_REP; ++m)
                #pragma unroll
                for (int n = 0; n < N_REP; ++n)
                    acc[m][n] = __builtin_amdgcn_mfma_f32_16x16x32_bf16(af[m], bfr[n], acc[m][n], 0, 0, 0);
        }
    }

    float bv[N_REP];
    #pragma unroll
    for (int n = 0; n < N_REP; ++n) bv[n] = bias ? bias[wn0 + n * 16 + l15] : 0.f;

    #pragma unroll
    for (int m = 0; m < M_REP; ++m) {
        #pragma unroll
        for (int r = 0; r < 4; ++r) {
            int grow = r0 + wm * WROWS + m * 16 + lhi * 4 + r;
            if (grow < N) {
                #pragma unroll
                for (int n = 0; n < N_REP; ++n) {
                    int colr = wn0 + n * 16 + l15;
                    float v = acc[m][n][r] + bv[n];
                    if (RELU) v = fmaxf(v, 0.f);
                    if constexpr (OMODE != 3)
                        ((ushort*)outp)[(size_t)grow * OD + colr] = f2bf(v);
                    if constexpr (OMODE == 2 || OMODE == 3)
                        f8out[(size_t)grow * OD + colr] = f2e4m3(v);
                }
            }
        }
    }
}

// ---------- FUSED final layer: agg<64>(g2_q8) + (h @ Wr2^T + bl2 + agg) -> f32 out ----------
__global__ __launch_bounds__(256) void k_fin(const uchar* __restrict__ gq,
                                             const ushort* __restrict__ h_in,
                                             const ushort* __restrict__ W0,
                                             const float* __restrict__ bias,
                                             const int* __restrict__ rowptr,
                                             const int* __restrict__ col,
                                             float* __restrict__ outp, int N) {
    __shared__ __align__(16) ushort ga[128 * 64];  // aggregated means, plain layout
    __shared__ __align__(16) ushort sA[128 * 64];
    __shared__ __align__(16) ushort sW[64 * 64];

    const int t    = threadIdx.x;
    const int wid  = t >> 6;
    const int lane = t & 63;
    const int g    = lane >> 4;
    const int c16  = lane & 15;
    const int r0   = blockIdx.x * 128;

    // ---- phase 1: aggregate 128 node means (64-dim), masked packed gather ----
    for (int it = 0; it < 8; ++it) {
        int nl = it * 16 + wid * 4 + g;
        int node = r0 + nl;
        f32x2 a01 = {0.f, 0.f}, a23 = {0.f, 0.f};
        float inv = 1.f;
        if (node < N) {
            int beg = rowptr[node], end = rowptr[node + 1];
            inv = 1.f / fmaxf((float)(end - beg), 1.f);
            const uchar* base = gq + c16 * 4;
            for (int jb0 = beg; jb0 < end; jb0 += 8) {
                #pragma unroll
                for (int q = 0; q < 8; ++q) {
                    int j = jb0 + q;
                    int s = col[j < end ? j : end - 1];
                    uint v = *(const uint*)(base + (size_t)s * 64);
                    float m = (j < end) ? 1.f : 0.f;
                    f32x2 mk = {m, m};
                    a01 += mk * __builtin_amdgcn_cvt_pk_f32_fp8(v, false);
                    a23 += mk * __builtin_amdgcn_cvt_pk_f32_fp8(v, true);
                }
            }
        }
        uint2 o;
        o.x = (uint)f2bf(a01[0] * inv) | ((uint)f2bf(a01[1] * inv) << 16);
        o.y = (uint)f2bf(a23[0] * inv) | ((uint)f2bf(a23[1] * inv) << 16);
        *(uint2*)((char*)ga + nl * 128 + c16 * 8) = o;
    }

    const int l15 = lane & 15;
    const int lhi = lane >> 4;

    f32x4 zero = {0.f, 0.f, 0.f, 0.f};
    f32x4 acc[2][4];
    #pragma unroll
    for (int m = 0; m < 2; ++m)
        #pragma unroll
        for (int n = 0; n < 4; ++n) acc[m][n] = zero;

    for (int kc = 0; kc < 2; ++kc) {
        const int kloc = kc * 64;
        __syncthreads();   // kc=0: orders phase-1 ga writes for all threads
        #pragma unroll
        for (int it = 0; it < 4; ++it) {
            int slot = it * 256 + t;
            int row = slot >> 3, k8 = slot & 7;
            int gr = r0 + row; if (gr >= N) gr = N - 1;
            short8 v = *(const short8*)(h_in + (size_t)gr * 128 + kloc + k8 * 8);
            *(short8*)((char*)sA + ((row * 128 + k8 * 16) ^ ((row & 7) << 4))) = v;
        }
        #pragma unroll
        for (int it = 0; it < 2; ++it) {
            int slot = it * 256 + t;
            int row = slot >> 3, k8 = slot & 7;
            short8 v = *(const short8*)(W0 + (size_t)row * 128 + kloc + k8 * 8);
            *(short8*)((char*)sW + ((row * 128 + k8 * 16) ^ ((row & 7) << 4))) = v;
        }
        __syncthreads();

        #pragma unroll
        for (int kb = 0; kb < 2; ++kb) {
            short8 af[2], bfr[4];
            #pragma unroll
            for (int m = 0; m < 2; ++m) {
                int row = wid * 32 + m * 16 + l15;
                af[m] = *(const short8*)((const char*)sA +
                        ((row * 128 + kb * 64 + lhi * 16) ^ ((row & 7) << 4)));
            }
            #pragma unroll
            for (int n = 0; n < 4; ++n) {
                int colr = n * 16 + l15;
                bfr[n] = *(const short8*)((const char*)sW +
                         ((colr * 128 + kb * 64 + lhi * 16) ^ ((colr & 7) << 4)));
            }
            #pragma unroll
            for (int m = 0; m < 2; ++m)
                #pragma unroll
                for (int n = 0; n < 4; ++n)
                    acc[m][n] = __builtin_amdgcn_mfma_f32_16x16x32_bf16(af[m], bfr[n], acc[m][n], 0, 0, 0);
        }
    }

    float bv[4];
    #pragma unroll
    for (int n = 0; n < 4; ++n) bv[n] = bias[n * 16 + l15];

    #pragma unroll
    for (int m = 0; m < 2; ++m) {
        #pragma unroll
        for (int r = 0; r < 4; ++r) {
            int rl = wid * 32 + m * 16 + lhi * 4 + r;
            int grow = r0 + rl;
            if (grow < N) {
                #pragma unroll
                for (int n = 0; n < 4; ++n) {
                    int colr = n * 16 + l15;
                    float v = acc[m][n][r] + bv[n] + bf2f(ga[rl * 64 + colr]);
                    outp[(size_t)grow * 64 + colr] = v;
                }
            }
        }
    }
}

extern "C" void kernel_launch(void* const* d_in, const int* in_sizes, int n_in,
                              void* d_out, int out_size, void* d_ws, size_t ws_size,
                              hipStream_t stream) {
    const float* x     = (const float*)d_in[0];
    const int*   eidx  = (const int*)d_in[1];
    const float* emb_W = (const float*)d_in[2];
    const float* emb_b = (const float*)d_in[3];
    const float* Wl0   = (const float*)d_in[4];
    const float* bl0   = (const float*)d_in[5];
    const float* Wr0   = (const float*)d_in[6];
    const float* Wl1   = (const float*)d_in[7];
    const float* bl1   = (const float*)d_in[8];
    const float* Wr1   = (const float*)d_in[9];
    const float* Wl2   = (const float*)d_in[10];
    const float* bl2   = (const float*)d_in[11];
    const float* Wr2   = (const float*)d_in[12];

    const int N = in_sizes[0] / NODE_D;
    const int E = in_sizes[1] / 2;
    const int* src = eidx;
    const int* dst = eidx + E;
    const int NC = (E + ECH - 1) / ECH;
    const int NP = (N + (1 << PSH) - 1) >> PSH;

    // ---- workspace layout ----
    char* w = (char*)d_ws;
    ushort* h_bf    = (ushort*)w; w += (size_t)N * 128 * sizeof(ushort);
    ushort* mean_bf = (ushort*)w; w += (size_t)N * 128 * sizeof(ushort);
    ushort* wbf     = (ushort*)w; w += (size_t)98304 * sizeof(ushort);
    uchar* q8_a     = (uchar*)w;  w += (size_t)N * 128;
    uchar* q8_b     = (uchar*)w;  w += (size_t)N * 128;
    uint* ebuf      = (uint*)w;   w += (size_t)E * sizeof(uint);
    int* cm     = (int*)w; w += (size_t)NC * 256 * sizeof(int);
    int* om     = (int*)w; w += (size_t)NC * 256 * sizeof(int);
    int* pbase  = (int*)w; w += (size_t)(NP + 1) * sizeof(int);
    int* rowptr = (int*)w; w += (size_t)(N + 1) * sizeof(int);
    int* col    = (int*)w; w += (size_t)E * sizeof(int);

    // layer-2 fp8 pre-transform buffer aliases mean_bf (dead by then)
    uchar* g2_q8 = (uchar*)mean_bf;

    const ushort* embB = wbf;
    const ushort* Wl0B = wbf + 16384;
    const ushort* Wr0B = wbf + 32768;
    const ushort* Wl1B = wbf + 49152;
    const ushort* Wr1B = wbf + 65536;
    const ushort* Wl2B = wbf + 81920;
    const ushort* Wr2B = wbf + 90112;

    const int TPB = 256;

    // ---- CSR build: count -> pscan -> deterministic scatter -> per-partition local sort ----
    hipLaunchKernelGGL(k_count, dim3(NC + 384), dim3(TPB), 0, stream,
                       dst, cm, E, NC, emb_W, Wl0, Wr0, Wl1, Wr1, Wl2, Wr2, wbf);
    hipLaunchKernelGGL(k_pscan, dim3(1), dim3(TPB), 0, stream,
                       cm, om, pbase, rowptr + N, NC, NP, E);
    hipLaunchKernelGGL(k_scatter3, dim3(NC), dim3(TPB), 0, stream, src, dst, om, ebuf, E);
    hipLaunchKernelGGL(k_local, dim3(NP), dim3(TPB), 0, stream, ebuf, pbase, rowptr, col, N);

    const int dgrid = (N + 127) / 128;
    const int agrid = (N + 3) / 4;

    // ---- embedding: h = x @ emb_W.T + emb_b (bf16 + fp8 copy) ----
    hipLaunchKernelGGL((k_mm<128, false, false, 2, true>), dim3(dgrid), dim3(TPB), 0, stream,
                       (const void*)x, (const ushort*)nullptr, embB, (const ushort*)nullptr,
                       emb_b, h_bf, q8_a, N);

    // ---- layer 0: h = relu(mean@Wl0.T + bl0 + h@Wr0.T) (bf16 + fp8) ----
    hipLaunchKernelGGL(k_aggf, dim3(agrid), dim3(TPB), 0, stream, q8_a, rowptr, col, mean_bf, N);
    hipLaunchKernelGGL((k_mm<128, true, true, 2, false>), dim3(dgrid), dim3(TPB), 0, stream,
                       (const void*)mean_bf, h_bf, Wl0B, Wr0B, bl0, h_bf, q8_b, N);

    // ---- layer 1 (bf16 out only) ----
    hipLaunchKernelGGL(k_aggf, dim3(agrid), dim3(TPB), 0, stream, q8_b, rowptr, col, mean_bf, N);
    hipLaunchKernelGGL((k_mm<128, true, true, 0, false>), dim3(dgrid), dim3(TPB), 0, stream,
                       (const void*)mean_bf, h_bf, Wl1B, Wr1B, bl1, h_bf, (uchar*)nullptr, N);

    // ---- layer 2: pre-transform to fp8 (linearity), then fused agg<64> + root + add ----
    hipLaunchKernelGGL((k_mm<64, false, false, 3, false>), dim3(dgrid), dim3(TPB), 0, stream,
                       (const void*)h_bf, (const ushort*)nullptr, Wl2B, (const ushort*)nullptr,
                       (const float*)nullptr, (void*)nullptr, g2_q8, N);
    hipLaunchKernelGGL(k_fin, dim3(dgrid), dim3(TPB), 0, stream,
                       g2_q8, h_bf, Wr2B, bl2, rowptr, col, (float*)d_out, N);
}

// Round 13
// 253.035 us; speedup vs baseline: 1.3355x; 1.3355x over previous
//
#include <hip/hip_runtime.h>

typedef __attribute__((ext_vector_type(8))) short short8;
typedef __attribute__((ext_vector_type(4))) float f32x4;
typedef __attribute__((ext_vector_type(2))) float f32x2;

#define NODE_D 128
#define ECH 4096           // edges per counting/scatter chunk (small -> fill all CUs)
#define PSH 9              // partition = 512 consecutive dst nodes
// NOTE: pipeline assumes N <= 131072 (src packs into 17 bits; NP <= 256) and NC <= 512

__device__ __forceinline__ float bf2f(ushort u) {
    union { uint i; float f; } c; c.i = ((uint)u) << 16; return c.f;
}
__device__ __forceinline__ ushort f2bf(float f) {
    union { float f; uint i; } c; c.f = f;
    return (ushort)((c.i + 0x7FFF + ((c.i >> 16) & 1)) >> 16);
}
__device__ __forceinline__ uchar f2e4m3(float f) {
    uint w = (uint)__builtin_amdgcn_cvt_pk_fp8_f32(f, f, 0, false);
    return (uchar)(w & 0xff);
}

// ---------- fused: per-chunk partition histogram (blocks 0..NC) + weight cvt ----------
__global__ __launch_bounds__(256) void k_count(const int* __restrict__ dst,
                                               int* __restrict__ cm,
                                               int E, int NC,
                                               const float* __restrict__ s0, const float* __restrict__ s1,
                                               const float* __restrict__ s2, const float* __restrict__ s3,
                                               const float* __restrict__ s4, const float* __restrict__ s5,
                                               const float* __restrict__ s6, ushort* __restrict__ wdst) {
    if ((int)blockIdx.x >= NC) {
        int i = ((int)blockIdx.x - NC) * 256 + threadIdx.x;
        if (i >= 98304) return;
        const float* s; int off;
        if (i < 16384)      { s = s0; off = i; }
        else if (i < 32768) { s = s1; off = i - 16384; }
        else if (i < 49152) { s = s2; off = i - 32768; }
        else if (i < 65536) { s = s3; off = i - 49152; }
        else if (i < 81920) { s = s4; off = i - 65536; }
        else if (i < 90112) { s = s5; off = i - 81920; }
        else                { s = s6; off = i - 90112; }
        wdst[i] = f2bf(s[off]);
        return;
    }
    __shared__ int lh[256];
    lh[threadIdx.x] = 0;
    __syncthreads();
    int c = blockIdx.x;
    int lo = c * ECH, hi = min(lo + ECH, E);
    for (int i = lo + (int)threadIdx.x; i < hi; i += 256)
        atomicAdd(&lh[dst[i] >> PSH], 1);
    __syncthreads();
    cm[c * 256 + threadIdx.x] = lh[threadIdx.x];
}

// ---------- per-partition scan over chunks: om (pbase-relative) + psum ----------
// Block p: exclusive prefix over c of cm[c*256+p], NC <= 512 (two 256-wide passes).
__global__ __launch_bounds__(256) void k_oscan(const int* __restrict__ cm,
                                               int* __restrict__ om,
                                               int* __restrict__ psum, int NC) {
    __shared__ int ts[256];
    int p = blockIdx.x;
    int t = threadIdx.x;
    int v0 = (t < NC) ? cm[t * 256 + p] : 0;
    int v1 = (t + 256 < NC) ? cm[(t + 256) * 256 + p] : 0;
    ts[t] = v0;
    __syncthreads();
    for (int st = 1; st < 256; st <<= 1) {
        int add = (t >= st) ? ts[t - st] : 0;
        __syncthreads();
        ts[t] += add;
        __syncthreads();
    }
    int incl0 = ts[t];
    int total0 = ts[255];
    __syncthreads();
    ts[t] = v1;
    __syncthreads();
    for (int st = 1; st < 256; st <<= 1) {
        int add = (t >= st) ? ts[t - st] : 0;
        __syncthreads();
        ts[t] += add;
        __syncthreads();
    }
    int incl1 = ts[t] + total0;
    if (t < NC) om[t * 256 + p] = incl0 - v0;
    if (t + 256 < NC) om[(t + 256) * 256 + p] = incl1 - v1;
    if (t == 255) psum[p] = total0 + ts[255];
}

// ---------- single small block: exclusive scan of psum -> pbase ----------
__global__ __launch_bounds__(256) void k_pbase(const int* __restrict__ psum,
                                               int* __restrict__ pbase,
                                               int* __restrict__ rowptrN,
                                               int NP, int E) {
    __shared__ int ts[256];
    int t = threadIdx.x;
    int v = (t < NP) ? psum[t] : 0;
    ts[t] = v;
    __syncthreads();
    for (int st = 1; st < 256; st <<= 1) {
        int add = (t >= st) ? ts[t - st] : 0;
        __syncthreads();
        ts[t] += add;
        __syncthreads();
    }
    if (t < NP) pbase[t] = ts[t] - v;
    if (t == 0) { pbase[NP] = E; rowptrN[0] = E; }
}

// ---------- deterministic scatter: edges -> partition-major packed ebuf ----------
// packed: bits 0-16 = src, bits 17-25 = local node (d & 511)
__global__ __launch_bounds__(256) void k_scatter3(const int* __restrict__ src,
                                                  const int* __restrict__ dst,
                                                  const int* __restrict__ om,
                                                  const int* __restrict__ pbase,
                                                  uint* __restrict__ ebuf, int E, int NP) {
    __shared__ int cur[256];
    int c = blockIdx.x;
    int pb = (threadIdx.x < NP) ? pbase[threadIdx.x] : 0;
    cur[threadIdx.x] = om[c * 256 + threadIdx.x] + pb;
    __syncthreads();
    int lo = c * ECH, hi = min(lo + ECH, E);
    for (int i = lo + (int)threadIdx.x; i < hi; i += 256) {
        int d = dst[i];
        int pos = atomicAdd(&cur[d >> PSH], 1);
        ebuf[pos] = ((uint)(d & 511) << 17) | (uint)src[i];
    }
}

// ---------- per-partition local CSR: LDS hist -> LDS scan -> rowptr + col ----------
__global__ __launch_bounds__(256) void k_local(const uint* __restrict__ ebuf,
                                               const int* __restrict__ pbase,
                                               int* __restrict__ rowptr,
                                               int* __restrict__ col, int N) {
    __shared__ int hist[512];
    __shared__ int cur[512];
    __shared__ int ts[256];
    int p = blockIdx.x;
    int t = threadIdx.x;
    int lo = pbase[p], hi = pbase[p + 1];
    hist[t] = 0; hist[t + 256] = 0;
    __syncthreads();
    for (int j = lo + t; j < hi; j += 256)
        atomicAdd(&hist[ebuf[j] >> 17], 1);
    __syncthreads();
    int v0 = hist[2 * t], v1 = hist[2 * t + 1];
    int s = v0 + v1;
    ts[t] = s;
    __syncthreads();
    for (int st = 1; st < 256; st <<= 1) {
        int add = (t >= st) ? ts[t - st] : 0;
        __syncthreads();
        ts[t] += add;
        __syncthreads();
    }
    int excl = ts[t] - s + lo;
    int node0 = (p << PSH) + 2 * t;
    if (node0 < N) rowptr[node0] = excl;
    if (node0 + 1 < N) rowptr[node0 + 1] = excl + v0;
    cur[2 * t] = excl;
    cur[2 * t + 1] = excl + v0;
    __syncthreads();
    for (int j = lo + t; j < hi; j += 256) {
        uint e = ebuf[j];
        int pos = atomicAdd(&cur[e >> 17], 1);
        col[pos] = (int)(e & 0x1FFFF);
    }
}

// ---------- mean aggregation over fp8, packed-VALU masked gather ----------
// 16 lanes x uint2 (8 fp8 cols) cover a 128B row; 4 edge-groups per wave,
// window 8 edges; f32x2 accumulators -> v_pk_fma; reduce via shfl_xor 16/32.
__global__ __launch_bounds__(256) void k_aggf(const uchar* __restrict__ hq,
                                              const int* __restrict__ rowptr,
                                              const int* __restrict__ col,
                                              ushort* __restrict__ mean, int N) {
    int node = blockIdx.x * 4 + (threadIdx.x >> 6);
    if (node >= N) return;
    int lane = threadIdx.x & 63;
    int grp  = lane >> 4;          // 4 edge groups
    int l16  = lane & 15;
    int beg = rowptr[node];
    int end = rowptr[node + 1];
    float inv = 1.f / fmaxf((float)(end - beg), 1.f);
    const uchar* base = hq + l16 * 8;
    f32x2 a01 = {0.f, 0.f}, a23 = {0.f, 0.f}, a45 = {0.f, 0.f}, a67 = {0.f, 0.f};
    for (int jb0 = beg; jb0 < end; jb0 += 8) {
        #pragma unroll
        for (int q = 0; q < 2; ++q) {
            int j = jb0 + grp * 2 + q;
            int s = col[j < end ? j : end - 1];
            uint2 v = *(const uint2*)(base + (size_t)s * 128);
            float m = (j < end) ? 1.f : 0.f;
            f32x2 mk = {m, m};
            a01 += mk * __builtin_amdgcn_cvt_pk_f32_fp8(v.x, false);
            a23 += mk * __builtin_amdgcn_cvt_pk_f32_fp8(v.x, true);
            a45 += mk * __builtin_amdgcn_cvt_pk_f32_fp8(v.y, false);
            a67 += mk * __builtin_amdgcn_cvt_pk_f32_fp8(v.y, true);
        }
    }
    float r[8] = {a01[0], a01[1], a23[0], a23[1], a45[0], a45[1], a67[0], a67[1]};
    #pragma unroll
    for (int i = 0; i < 8; ++i) {
        r[i] += __shfl_xor(r[i], 16);
        r[i] += __shfl_xor(r[i], 32);
    }
    if (lane < 16) {
        uint4 o;
        o.x = (uint)f2bf(r[0] * inv) | ((uint)f2bf(r[1] * inv) << 16);
        o.y = (uint)f2bf(r[2] * inv) | ((uint)f2bf(r[3] * inv) << 16);
        o.z = (uint)f2bf(r[4] * inv) | ((uint)f2bf(r[5] * inv) << 16);
        o.w = (uint)f2bf(r[6] * inv) | ((uint)f2bf(r[7] * inv) << 16);
        *(uint4*)(mean + (size_t)node * 128 + l16 * 8) = o;
    }
}

// ---------- MFMA dense: out = A0@W0^T (+ A1@W1^T) [+bias] [+relu] ----------
// OMODE: 0=bf16, 2=bf16+fp8copy, 3=fp8 only.
template<int OD, bool DUAL, bool RELU, int OMODE, bool A0F32>
__global__ __launch_bounds__(256) void k_mm(const void* __restrict__ A0,
                                            const ushort* __restrict__ A1,
                                            const ushort* __restrict__ W0,
                                            const ushort* __restrict__ W1,
                                            const float* __restrict__ bias,
                                            void* __restrict__ outp,
                                            uchar* __restrict__ f8out, int N) {
    constexpr int NK    = DUAL ? 4 : 2;
    constexpr int M_REP = (OD == 128) ? 4 : 2;
    constexpr int N_REP = 4;
    constexpr int WROWS = M_REP * 16;

    __shared__ __align__(16) ushort sA[128 * 64];
    __shared__ __align__(16) ushort sW[OD * 64];

    const int t    = threadIdx.x;
    const int wid  = t >> 6;
    const int lane = t & 63;
    const int l15  = lane & 15;
    const int lhi  = lane >> 4;
    const int r0   = blockIdx.x * 128;

    int wm, wn0;
    if (OD == 128) { wm = wid >> 1; wn0 = (wid & 1) * 64; }
    else           { wm = wid;      wn0 = 0; }

    f32x4 zero = {0.f, 0.f, 0.f, 0.f};
    f32x4 acc[M_REP][N_REP];
    #pragma unroll
    for (int m = 0; m < M_REP; ++m)
        #pragma unroll
        for (int n = 0; n < N_REP; ++n) acc[m][n] = zero;

    const ushort* A0b = (const ushort*)A0;
    const float*  A0f = (const float*)A0;

    for (int kc = 0; kc < NK; ++kc) {
        const ushort* Ws = (DUAL && kc >= 2) ? W1 : W0;
        const ushort* As = (DUAL && kc >= 2) ? A1 : A0b;
        const int kloc = (kc & 1) * 64;

        __syncthreads();
        #pragma unroll
        for (int it = 0; it < 4; ++it) {
            int slot = it * 256 + t;
            int row = slot >> 3, k8 = slot & 7;
            int gr = r0 + row; if (gr >= N) gr = N - 1;
            short8 v;
            if (A0F32 && kc < 2) {
                float4 p = *(const float4*)(A0f + (size_t)gr * 128 + kloc + k8 * 8);
                float4 q = *(const float4*)(A0f + (size_t)gr * 128 + kloc + k8 * 8 + 4);
                v[0] = (short)f2bf(p.x); v[1] = (short)f2bf(p.y);
                v[2] = (short)f2bf(p.z); v[3] = (short)f2bf(p.w);
                v[4] = (short)f2bf(q.x); v[5] = (short)f2bf(q.y);
                v[6] = (short)f2bf(q.z); v[7] = (short)f2bf(q.w);
            } else {
                v = *(const short8*)(As + (size_t)gr * 128 + kloc + k8 * 8);
            }
            *(short8*)((char*)sA + ((row * 128 + k8 * 16) ^ ((row & 7) << 4))) = v;
        }
        #pragma unroll
        for (int it = 0; it < OD / 32; ++it) {
            int slot = it * 256 + t;
            int row = slot >> 3, k8 = slot & 7;
            short8 v = *(const short8*)(Ws + (size_t)row * 128 + kloc + k8 * 8);
            *(short8*)((char*)sW + ((row * 128 + k8 * 16) ^ ((row & 7) << 4))) = v;
        }
        __syncthreads();

        #pragma unroll
        for (int kb = 0; kb < 2; ++kb) {
            short8 af[M_REP], bfr[N_REP];
            #pragma unroll
            for (int m = 0; m < M_REP; ++m) {
                int row = wm * WROWS + m * 16 + l15;
                af[m] = *(const short8*)((const char*)sA +
                        ((row * 128 + kb * 64 + lhi * 16) ^ ((row & 7) << 4)));
            }
            #pragma unroll
            for (int n = 0; n < N_REP; ++n) {
                int colr = wn0 + n * 16 + l15;
                bfr[n] = *(const short8*)((const char*)sW +
                         ((colr * 128 + kb * 64 + lhi * 16) ^ ((colr & 7) << 4)));
            }
            #pragma unroll
            for (int m = 0; m < M_REP; ++m)
                #pragma unroll
                for (int n = 0; n < N_REP; ++n)
                    acc[m][n] = __builtin_amdgcn_mfma_f32_16x16x32_bf16(af[m], bfr[n], acc[m][n], 0, 0, 0);
        }
    }

    float bv[N_REP];
    #pragma unroll
    for (int n = 0; n < N_REP; ++n) bv[n] = bias ? bias[wn0 + n * 16 + l15] : 0.f;

    #pragma unroll
    for (int m = 0; m < M_REP; ++m) {
        #pragma unroll
        for (int r = 0; r < 4; ++r) {
            int grow = r0 + wm * WROWS + m * 16 + lhi * 4 + r;
            if (grow < N) {
                #pragma unroll
                for (int n = 0; n < N_REP; ++n) {
                    int colr = wn0 + n * 16 + l15;
                    float v = acc[m][n][r] + bv[n];
                    if (RELU) v = fmaxf(v, 0.f);
                    if constexpr (OMODE != 3)
                        ((ushort*)outp)[(size_t)grow * OD + colr] = f2bf(v);
                    if constexpr (OMODE == 2 || OMODE == 3)
                        f8out[(size_t)grow * OD + colr] = f2e4m3(v);
                }
            }
        }
    }
}

// ---------- FUSED final layer: agg<64>(g2_q8) + (h @ Wr2^T + bl2 + agg) -> f32 out ----------
__global__ __launch_bounds__(256) void k_fin(const uchar* __restrict__ gq,
                                             const ushort* __restrict__ h_in,
                                             const ushort* __restrict__ W0,
                                             const float* __restrict__ bias,
                                             const int* __restrict__ rowptr,
                                             const int* __restrict__ col,
                                             float* __restrict__ outp, int N) {
    __shared__ __align__(16) ushort ga[128 * 64];  // aggregated means, plain layout
    __shared__ __align__(16) ushort sA[128 * 64];
    __shared__ __align__(16) ushort sW[64 * 64];

    const int t    = threadIdx.x;
    const int wid  = t >> 6;
    const int lane = t & 63;
    const int g    = lane >> 4;
    const int c16  = lane & 15;
    const int r0   = blockIdx.x * 128;

    // ---- phase 1: aggregate 128 node means (64-dim), masked packed gather ----
    for (int it = 0; it < 8; ++it) {
        int nl = it * 16 + wid * 4 + g;
        int node = r0 + nl;
        f32x2 a01 = {0.f, 0.f}, a23 = {0.f, 0.f};
        float inv = 1.f;
        if (node < N) {
            int beg = rowptr[node], end = rowptr[node + 1];
            inv = 1.f / fmaxf((float)(end - beg), 1.f);
            const uchar* base = gq + c16 * 4;
            for (int jb0 = beg; jb0 < end; jb0 += 8) {
                #pragma unroll
                for (int q = 0; q < 8; ++q) {
                    int j = jb0 + q;
                    int s = col[j < end ? j : end - 1];
                    uint v = *(const uint*)(base + (size_t)s * 64);
                    float m = (j < end) ? 1.f : 0.f;
                    f32x2 mk = {m, m};
                    a01 += mk * __builtin_amdgcn_cvt_pk_f32_fp8(v, false);
                    a23 += mk * __builtin_amdgcn_cvt_pk_f32_fp8(v, true);
                }
            }
        }
        uint2 o;
        o.x = (uint)f2bf(a01[0] * inv) | ((uint)f2bf(a01[1] * inv) << 16);
        o.y = (uint)f2bf(a23[0] * inv) | ((uint)f2bf(a23[1] * inv) << 16);
        *(uint2*)((char*)ga + nl * 128 + c16 * 8) = o;
    }

    const int l15 = lane & 15;
    const int lhi = lane >> 4;

    f32x4 zero = {0.f, 0.f, 0.f, 0.f};
    f32x4 acc[2][4];
    #pragma unroll
    for (int m = 0; m < 2; ++m)
        #pragma unroll
        for (int n = 0; n < 4; ++n) acc[m][n] = zero;

    for (int kc = 0; kc < 2; ++kc) {
        const int kloc = kc * 64;
        __syncthreads();   // kc=0: orders phase-1 ga writes for all threads
        #pragma unroll
        for (int it = 0; it < 4; ++it) {
            int slot = it * 256 + t;
            int row = slot >> 3, k8 = slot & 7;
            int gr = r0 + row; if (gr >= N) gr = N - 1;
            short8 v = *(const short8*)(h_in + (size_t)gr * 128 + kloc + k8 * 8);
            *(short8*)((char*)sA + ((row * 128 + k8 * 16) ^ ((row & 7) << 4))) = v;
        }
        #pragma unroll
        for (int it = 0; it < 2; ++it) {
            int slot = it * 256 + t;
            int row = slot >> 3, k8 = slot & 7;
            short8 v = *(const short8*)(W0 + (size_t)row * 128 + kloc + k8 * 8);
            *(short8*)((char*)sW + ((row * 128 + k8 * 16) ^ ((row & 7) << 4))) = v;
        }
        __syncthreads();

        #pragma unroll
        for (int kb = 0; kb < 2; ++kb) {
            short8 af[2], bfr[4];
            #pragma unroll
            for (int m = 0; m < 2; ++m) {
                int row = wid * 32 + m * 16 + l15;
                af[m] = *(const short8*)((const char*)sA +
                        ((row * 128 + kb * 64 + lhi * 16) ^ ((row & 7) << 4)));
            }
            #pragma unroll
            for (int n = 0; n < 4; ++n) {
                int colr = n * 16 + l15;
                bfr[n] = *(const short8*)((const char*)sW +
                         ((colr * 128 + kb * 64 + lhi * 16) ^ ((colr & 7) << 4)));
            }
            #pragma unroll
            for (int m = 0; m < 2; ++m)
                #pragma unroll
                for (int n = 0; n < 4; ++n)
                    acc[m][n] = __builtin_amdgcn_mfma_f32_16x16x32_bf16(af[m], bfr[n], acc[m][n], 0, 0, 0);
        }
    }

    float bv[4];
    #pragma unroll
    for (int n = 0; n < 4; ++n) bv[n] = bias[n * 16 + l15];

    #pragma unroll
    for (int m = 0; m < 2; ++m) {
        #pragma unroll
        for (int r = 0; r < 4; ++r) {
            int rl = wid * 32 + m * 16 + lhi * 4 + r;
            int grow = r0 + rl;
            if (grow < N) {
                #pragma unroll
                for (int n = 0; n < 4; ++n) {
                    int colr = n * 16 + l15;
                    float v = acc[m][n][r] + bv[n] + bf2f(ga[rl * 64 + colr]);
                    outp[(size_t)grow * 64 + colr] = v;
                }
            }
        }
    }
}

extern "C" void kernel_launch(void* const* d_in, const int* in_sizes, int n_in,
                              void* d_out, int out_size, void* d_ws, size_t ws_size,
                              hipStream_t stream) {
    const float* x     = (const float*)d_in[0];
    const int*   eidx  = (const int*)d_in[1];
    const float* emb_W = (const float*)d_in[2];
    const float* emb_b = (const float*)d_in[3];
    const float* Wl0   = (const float*)d_in[4];
    const float* bl0   = (const float*)d_in[5];
    const float* Wr0   = (const float*)d_in[6];
    const float* Wl1   = (const float*)d_in[7];
    const float* bl1   = (const float*)d_in[8];
    const float* Wr1   = (const float*)d_in[9];
    const float* Wl2   = (const float*)d_in[10];
    const float* bl2   = (const float*)d_in[11];
    const float* Wr2   = (const float*)d_in[12];

    const int N = in_sizes[0] / NODE_D;
    const int E = in_sizes[1] / 2;
    const int* src = eidx;
    const int* dst = eidx + E;
    const int NC = (E + ECH - 1) / ECH;
    const int NP = (N + (1 << PSH) - 1) >> PSH;

    // ---- workspace layout ----
    char* w = (char*)d_ws;
    ushort* h_bf    = (ushort*)w; w += (size_t)N * 128 * sizeof(ushort);
    ushort* mean_bf = (ushort*)w; w += (size_t)N * 128 * sizeof(ushort);
    ushort* wbf     = (ushort*)w; w += (size_t)98304 * sizeof(ushort);
    uchar* q8_a     = (uchar*)w;  w += (size_t)N * 128;
    uchar* q8_b     = (uchar*)w;  w += (size_t)N * 128;
    uint* ebuf      = (uint*)w;   w += (size_t)E * sizeof(uint);
    int* cm     = (int*)w; w += (size_t)NC * 256 * sizeof(int);
    int* om     = (int*)w; w += (size_t)NC * 256 * sizeof(int);
    int* psum   = (int*)w; w += (size_t)256 * sizeof(int);
    int* pbase  = (int*)w; w += (size_t)(NP + 1) * sizeof(int);
    int* rowptr = (int*)w; w += (size_t)(N + 1) * sizeof(int);
    int* col    = (int*)w; w += (size_t)E * sizeof(int);

    // layer-2 fp8 pre-transform buffer aliases mean_bf (dead by then)
    uchar* g2_q8 = (uchar*)mean_bf;

    const ushort* embB = wbf;
    const ushort* Wl0B = wbf + 16384;
    const ushort* Wr0B = wbf + 32768;
    const ushort* Wl1B = wbf + 49152;
    const ushort* Wr1B = wbf + 65536;
    const ushort* Wl2B = wbf + 81920;
    const ushort* Wr2B = wbf + 90112;

    const int TPB = 256;

    // ---- CSR build: count -> oscan/pbase -> deterministic scatter -> local sort ----
    hipLaunchKernelGGL(k_count, dim3(NC + 384), dim3(TPB), 0, stream,
                       dst, cm, E, NC, emb_W, Wl0, Wr0, Wl1, Wr1, Wl2, Wr2, wbf);
    hipLaunchKernelGGL(k_oscan, dim3(NP), dim3(TPB), 0, stream, cm, om, psum, NC);
    hipLaunchKernelGGL(k_pbase, dim3(1), dim3(TPB), 0, stream, psum, pbase, rowptr + N, NP, E);
    hipLaunchKernelGGL(k_scatter3, dim3(NC), dim3(TPB), 0, stream, src, dst, om, pbase, ebuf, E, NP);
    hipLaunchKernelGGL(k_local, dim3(NP), dim3(TPB), 0, stream, ebuf, pbase, rowptr, col, N);

    const int dgrid = (N + 127) / 128;
    const int agrid = (N + 3) / 4;

    // ---- embedding: h = x @ emb_W.T + emb_b (bf16 + fp8 copy) ----
    hipLaunchKernelGGL((k_mm<128, false, false, 2, true>), dim3(dgrid), dim3(TPB), 0, stream,
                       (const void*)x, (const ushort*)nullptr, embB, (const ushort*)nullptr,
                       emb_b, h_bf, q8_a, N);

    // ---- layer 0: h = relu(mean@Wl0.T + bl0 + h@Wr0.T) (bf16 + fp8) ----
    hipLaunchKernelGGL(k_aggf, dim3(agrid), dim3(TPB), 0, stream, q8_a, rowptr, col, mean_bf, N);
    hipLaunchKernelGGL((k_mm<128, true, true, 2, false>), dim3(dgrid), dim3(TPB), 0, stream,
                       (const void*)mean_bf, h_bf, Wl0B, Wr0B, bl0, h_bf, q8_b, N);

    // ---- layer 1 (bf16 out only) ----
    hipLaunchKernelGGL(k_aggf, dim3(agrid), dim3(TPB), 0, stream, q8_b, rowptr, col, mean_bf, N);
    hipLaunchKernelGGL((k_mm<128, true, true, 0, false>), dim3(dgrid), dim3(TPB), 0, stream,
                       (const void*)mean_bf, h_bf, Wl1B, Wr1B, bl1, h_bf, (uchar*)nullptr, N);

    // ---- layer 2: pre-transform to fp8 (linearity), then fused agg<64> + root + add ----
    hipLaunchKernelGGL((k_mm<64, false, false, 3, false>), dim3(dgrid), dim3(TPB), 0, stream,
                       (const void*)h_bf, (const ushort*)nullptr, Wl2B, (const ushort*)nullptr,
                       (const float*)nullptr, (void*)nullptr, g2_q8, N);
    hipLaunchKernelGGL(k_fin, dim3(dgrid), dim3(TPB), 0, stream,
                       g2_q8, h_bf, Wr2B, bl2, rowptr, col, (float*)d_out, N);
}